// Round 3
// baseline (7607.465 us; speedup 1.0000x reference)
//
#include <hip/hip_runtime.h>

#define SEQ_LEN 256
#define SPIKE_STEPS 7
#define BATCH 128
#define IN_DIM 96
#define HIDDEN 512
#define OUT_DIM 2

// d_ws layout: W0T [96*512] | W1T [512*512] | W2T [512*512] | ctr[128] ints | zbuf[B][256 win][56] u64
#define W0T_OFF 0
#define W1T_OFF (IN_DIM * HIDDEN)
#define W2T_OFF (W1T_OFF + HIDDEN * HIDDEN)
#define CTR_BYTE_OFF ((size_t)(W2T_OFF + HIDDEN * HIDDEN) * sizeof(float))
#define ZBUF_BYTE_OFF (CTR_BYTE_OFF + 1024)

__global__ void transpose_kernel(const float* __restrict__ in, float* __restrict__ out,
                                 int rows, int cols) {
    int idx = blockIdx.x * blockDim.x + threadIdx.x;
    if (idx < rows * cols) {
        int r = idx / cols, c = idx - r * cols;
        out[c * rows + r] = in[idx];
    }
}

// Window-batched 2-stage pipeline.
// Producer (even blocks): layer0's 7-step spike pattern is computable upfront
// (cur0 const within a window). Rows of W1 active at ANY of the 7 steps are
// loaded ONCE and added into 7 per-step accumulators guarded by the row's
// fire pattern (j-outer, t-inner => each step's sum is ascending-j =>
// bit-identical to per-step summation). Then mem1 evolves 7 steps and the 7
// z1 masks are published per-window. Consumer (odd blocks): same trick for W2.
#define ACCUM(P, W) \
    { if ((P) & 1)   c0 = __fadd_rn(c0, (W)); \
      if ((P) & 2)   c1 = __fadd_rn(c1, (W)); \
      if ((P) & 4)   c2 = __fadd_rn(c2, (W)); \
      if ((P) & 8)   c3 = __fadd_rn(c3, (W)); \
      if ((P) & 16)  c4 = __fadd_rn(c4, (W)); \
      if ((P) & 32)  c5 = __fadd_rn(c5, (W)); \
      if ((P) & 64)  c6 = __fadd_rn(c6, (W)); }

__launch_bounds__(512, 1)
__global__ void snn_win_kernel(const float* __restrict__ x,     // [256,128,96]
                               const float* __restrict__ Wout,  // [2,512]
                               const float* __restrict__ betas, // [3]
                               const float* __restrict__ thrs,  // [3]
                               const float* __restrict__ W0T,   // [96,512]
                               const float* __restrict__ W1T,   // [512,512]
                               const float* __restrict__ W2T,   // [512,512]
                               unsigned long long* __restrict__ zbuf,
                               int* __restrict__ ctr,
                               float* __restrict__ out)         // [256,128,2]
{
    const int b    = blockIdx.x >> 1;
    const int role = blockIdx.x & 1;
    const int tid  = threadIdx.x;
    const int lane = tid & 63;
    const int wid  = tid >> 6;

    __shared__ float xs[IN_DIM];
    __shared__ unsigned long long zm[8];    // ballot scratch for compaction
    __shared__ int act[HIDDEN];             // rec = j | (pattern<<16), ascending j
    __shared__ unsigned long long zpub[56]; // consumer: 7 t x 8 waves
    __shared__ float red[7 * 16];           // consumer: per-t, 8 waves x 2 outs

    if (role == 0) {
        // ======================= producer: layer0 + layer1 =======================
        const float beta0 = betas[0], beta1 = betas[1];
        const float thr0  = thrs[0],  thr1  = thrs[1];
        float mem0 = 0.f, mem1 = 0.f;
        unsigned long long* zb = zbuf + (size_t)b * SEQ_LEN * 56;

        for (int i = 0; i < SEQ_LEN; ++i) {
            if (tid < IN_DIM) xs[tid] = x[(i * BATCH + b) * IN_DIM + tid];
            __syncthreads();  // B0

            float cur0 = 0.f;
            #pragma unroll 8
            for (int k = 0; k < IN_DIM; ++k)
                cur0 = __fmaf_rn(xs[k], W0T[k * HIDDEN + tid], cur0);

            // ---- layer0: full 7-step evolution -> fire pattern (per h = tid) ----
            int pat0 = 0;
            {
                float m = mem0;
                #pragma unroll
                for (int t = 0; t < SPIKE_STEPS; ++t) {
                    bool rs = (m - thr0) > 0.f;
                    m = rs ? 0.f : __fadd_rn(__fmul_rn(beta0, m), cur0);
                    bool z = (m - thr0) > 0.f;
                    pat0 |= ((int)z) << t;
                }
                mem0 = m;
            }

            // ---- compact ascending union list (rows active at any t) ----
            bool active = (pat0 != 0);
            {
                unsigned long long bal = __ballot(active);
                if (lane == 0) zm[wid] = bal;
            }
            __syncthreads();  // B1
            int nact;
            {
                int pre = 0, total = 0;
                #pragma unroll
                for (int q = 0; q < 8; ++q) {
                    int p = __popcll(zm[q]);
                    total += p;
                    if (q < wid) pre += p;
                }
                int rank = pre + __popcll(zm[wid] & ((1ull << lane) - 1ull));
                if (active) act[rank] = tid | (pat0 << 16);
                nact = total;
            }
            __syncthreads();  // B2

            // ---- layer1 currents for all 7 steps in one pass over union rows ----
            float c0 = 0.f, c1 = 0.f, c2 = 0.f, c3 = 0.f, c4 = 0.f, c5 = 0.f, c6 = 0.f;
            {
                int n = 0;
                for (; n + 1 < nact; n += 2) {
                    int rA = act[n], rB = act[n + 1];
                    float wA = W1T[(rA & 0xffff) * HIDDEN + tid];
                    float wB = W1T[(rB & 0xffff) * HIDDEN + tid];
                    int pA = __builtin_amdgcn_readfirstlane(rA) >> 16;
                    int pB = __builtin_amdgcn_readfirstlane(rB) >> 16;
                    ACCUM(pA, wA);
                    ACCUM(pB, wB);
                }
                if (n < nact) {
                    int rA = act[n];
                    float wA = W1T[(rA & 0xffff) * HIDDEN + tid];
                    int pA = __builtin_amdgcn_readfirstlane(rA) >> 16;
                    ACCUM(pA, wA);
                }
            }

            // ---- layer1: 7-step evolution, publish z1 masks for the window ----
            const size_t wbase = (size_t)i * 56;
            {
                float curs[SPIKE_STEPS] = {c0, c1, c2, c3, c4, c5, c6};
                float m = mem1;
                #pragma unroll
                for (int t = 0; t < SPIKE_STEPS; ++t) {
                    bool rs = (m - thr1) > 0.f;
                    m = rs ? 0.f : __fadd_rn(__fmul_rn(beta1, m), curs[t]);
                    bool z = (m - thr1) > 0.f;
                    unsigned long long bal = __ballot(z);
                    if (lane == 0)
                        __hip_atomic_store(&zb[wbase + t * 8 + wid], bal,
                                           __ATOMIC_RELAXED, __HIP_MEMORY_SCOPE_AGENT);
                }
                mem1 = m;
            }
            __syncthreads();  // B3: vmcnt(0) drain -> masks at coherent point
            if (tid == 0)
                __hip_atomic_store(&ctr[b], i + 1,
                                   __ATOMIC_RELAXED, __HIP_MEMORY_SCOPE_AGENT);
        }
    } else {
        // ======================= consumer: layer2 + output =======================
        const float beta2 = betas[2];
        const float thr2  = thrs[2];
        const float wo0 = Wout[tid];
        const float wo1 = Wout[HIDDEN + tid];
        float mem2 = 0.f, mo0 = 0.f, mo1 = 0.f;
        const unsigned long long* zb = zbuf + (size_t)b * SEQ_LEN * 56;

        for (int i = 0; i < SEQ_LEN; ++i) {
            if (tid == 0) {
                while (__hip_atomic_load(&ctr[b], __ATOMIC_RELAXED,
                                         __HIP_MEMORY_SCOPE_AGENT) < i + 1)
                    __builtin_amdgcn_s_sleep(1);
            }
            __syncthreads();  // B0

            if (tid < 56)
                zpub[tid] = __hip_atomic_load(&zb[(size_t)i * 56 + tid],
                                              __ATOMIC_RELAXED, __HIP_MEMORY_SCOPE_AGENT);
            __syncthreads();  // B1

            // per-h window fire pattern of layer1
            int pat = 0;
            #pragma unroll
            for (int t = 0; t < SPIKE_STEPS; ++t)
                pat |= (int)((zpub[t * 8 + wid] >> lane) & 1ull) << t;

            bool active = (pat != 0);
            {
                unsigned long long bal = __ballot(active);
                if (lane == 0) zm[wid] = bal;
            }
            __syncthreads();  // B2
            int nact;
            {
                int pre = 0, total = 0;
                #pragma unroll
                for (int q = 0; q < 8; ++q) {
                    int p = __popcll(zm[q]);
                    total += p;
                    if (q < wid) pre += p;
                }
                int rank = pre + __popcll(zm[wid] & ((1ull << lane) - 1ull));
                if (active) act[rank] = tid | (pat << 16);
                nact = total;
            }
            __syncthreads();  // B3

            // ---- layer2 currents for all 7 steps ----
            float c0 = 0.f, c1 = 0.f, c2 = 0.f, c3 = 0.f, c4 = 0.f, c5 = 0.f, c6 = 0.f;
            {
                int n = 0;
                for (; n + 1 < nact; n += 2) {
                    int rA = act[n], rB = act[n + 1];
                    float wA = W2T[(rA & 0xffff) * HIDDEN + tid];
                    float wB = W2T[(rB & 0xffff) * HIDDEN + tid];
                    int pA = __builtin_amdgcn_readfirstlane(rA) >> 16;
                    int pB = __builtin_amdgcn_readfirstlane(rB) >> 16;
                    ACCUM(pA, wA);
                    ACCUM(pB, wB);
                }
                if (n < nact) {
                    int rA = act[n];
                    float wA = W2T[(rA & 0xffff) * HIDDEN + tid];
                    int pA = __builtin_amdgcn_readfirstlane(rA) >> 16;
                    ACCUM(pA, wA);
                }
            }

            // ---- layer2 evolution + per-t partial output into red[t] ----
            {
                float curs[SPIKE_STEPS] = {c0, c1, c2, c3, c4, c5, c6};
                float m = mem2;
                #pragma unroll
                for (int t = 0; t < SPIKE_STEPS; ++t) {
                    bool rs = (m - thr2) > 0.f;
                    m = rs ? 0.f : __fadd_rn(__fmul_rn(beta2, m), curs[t]);
                    bool z = (m - thr2) > 0.f;
                    float cc0 = z ? wo0 : 0.f;
                    float cc1 = z ? wo1 : 0.f;
                    #pragma unroll
                    for (int off = 32; off > 0; off >>= 1) {
                        cc0 += __shfl_down(cc0, off);
                        cc1 += __shfl_down(cc1, off);
                    }
                    if (lane == 0) { red[t * 16 + wid * 2] = cc0; red[t * 16 + wid * 2 + 1] = cc1; }
                }
                mem2 = m;
            }
            __syncthreads();  // B4

            if (tid == 0) {
                float so0 = 0.f, so1 = 0.f;
                #pragma unroll
                for (int t = 0; t < SPIKE_STEPS; ++t) {
                    float r0 = 0.f, r1 = 0.f;
                    #pragma unroll
                    for (int q = 0; q < 8; ++q) {
                        r0 += red[t * 16 + q * 2];
                        r1 += red[t * 16 + q * 2 + 1];
                    }
                    mo0 += r0; mo1 += r1;
                    so0 += mo0; so1 += mo1;
                }
                out[(i * BATCH + b) * OUT_DIM + 0] = so0 / 7.0f;
                out[(i * BATCH + b) * OUT_DIM + 1] = so1 / 7.0f;
            }
        }
    }
}

extern "C" void kernel_launch(void* const* d_in, const int* in_sizes, int n_in,
                              void* d_out, int out_size, void* d_ws, size_t ws_size,
                              hipStream_t stream) {
    const float* x     = (const float*)d_in[0];
    const float* W0    = (const float*)d_in[1];
    const float* W1    = (const float*)d_in[2];
    const float* W2    = (const float*)d_in[3];
    const float* Wout  = (const float*)d_in[4];
    const float* betas = (const float*)d_in[5];
    const float* thrs  = (const float*)d_in[6];
    float* out = (float*)d_out;

    float* ws  = (float*)d_ws;
    float* W0T = ws + W0T_OFF;
    float* W1T = ws + W1T_OFF;
    float* W2T = ws + W2T_OFF;
    int* ctr = (int*)((char*)d_ws + CTR_BYTE_OFF);
    unsigned long long* zbuf = (unsigned long long*)((char*)d_ws + ZBUF_BYTE_OFF);

    {
        int n = HIDDEN * IN_DIM;
        transpose_kernel<<<(n + 255) / 256, 256, 0, stream>>>(W0, W0T, HIDDEN, IN_DIM);
    }
    {
        int n = HIDDEN * HIDDEN;
        transpose_kernel<<<(n + 255) / 256, 256, 0, stream>>>(W1, W1T, HIDDEN, HIDDEN);
        transpose_kernel<<<(n + 255) / 256, 256, 0, stream>>>(W2, W2T, HIDDEN, HIDDEN);
    }

    hipMemsetAsync((char*)d_ws + CTR_BYTE_OFF, 0, 1024, stream);

    snn_win_kernel<<<2 * BATCH, HIDDEN, 0, stream>>>(
        x, Wout, betas, thrs, W0T, W1T, W2T, zbuf, ctr, out);
}

// Round 5
// 6285.515 us; speedup vs baseline: 1.2103x; 1.2103x over previous
//
#include <hip/hip_runtime.h>

#define SEQ_LEN 256
#define SPIKE_STEPS 7
#define T_TOTAL (SEQ_LEN * SPIKE_STEPS)
#define BATCH 128
#define IN_DIM 96
#define HIDDEN 512
#define OUT_DIM 2

#define REG_J 192   // weight rows [0,REG_J) cached in per-thread VGPRs (multiple of 64)

// d_ws layout: W0T [96*512] | W1T [512*512] | W2T [512*512] | ctr[128] | zbuf[B][T][8] u64
#define W0T_OFF 0
#define W1T_OFF (IN_DIM * HIDDEN)
#define W2T_OFF (W1T_OFF + HIDDEN * HIDDEN)
#define CTR_BYTE_OFF ((size_t)(W2T_OFF + HIDDEN * HIDDEN) * sizeof(float))
#define ZBUF_BYTE_OFF (CTR_BYTE_OFF + 1024)

__global__ void transpose_kernel(const float* __restrict__ in, float* __restrict__ out,
                                 int rows, int cols) {
    int idx = blockIdx.x * blockDim.x + threadIdx.x;
    if (idx < rows * cols) {
        int r = idx / cols, c = idx - r * cols;
        out[c * rows + r] = in[idx];
    }
}

// Round-2 two-stage pipeline (even blocks: layer0+layer1; odd: layer2+output),
// per-step sync, PLUS a register-cached weight prefix: rows j<REG_J of the
// role's matrix live in per-thread VGPRs (wr[j] = W[j][tid]); their
// contribution is added via wave-uniform mask bit-tests (no memory traffic).
// Rows j>=REG_J come from L2 via the compacted active list as in round 2.
// Prefix-then-suffix, both ascending-j => bit-identical to round 2.
__launch_bounds__(512, 2)
__global__ void snn_reg_kernel(const float* __restrict__ x,     // [256,128,96]
                               const float* __restrict__ Wout,  // [2,512]
                               const float* __restrict__ betas, // [3]
                               const float* __restrict__ thrs,  // [3]
                               const float* __restrict__ W0T,   // [96,512]
                               const float* __restrict__ W1T,   // [512,512]
                               const float* __restrict__ W2T,   // [512,512]
                               unsigned long long* __restrict__ zbuf,
                               int* __restrict__ ctr,
                               float* __restrict__ out)         // [256,128,2]
{
    const int b    = blockIdx.x >> 1;
    const int role = blockIdx.x & 1;
    const int tid  = threadIdx.x;
    const int lane = tid & 63;
    const int wid  = tid >> 6;

    __shared__ float xs[IN_DIM];
    __shared__ unsigned long long zmf[8];  // full 512-bit spike mask
    __shared__ unsigned long long zmc[8];  // filtered (j>=REG_J) mask for compaction
    __shared__ int act[HIDDEN];
    __shared__ float red[16];

    // ---- register-cached prefix of this role's weight matrix ----
    const float* __restrict__ Wmat = (role == 0) ? W1T : W2T;
    float wr[REG_J];
    #pragma unroll
    for (int j = 0; j < REG_J; ++j)
        wr[j] = Wmat[j * HIDDEN + tid];

    if (role == 0) {
        // ---------------- producer: layer0 + layer1 ----------------
        const float beta0 = betas[0], beta1 = betas[1];
        const float thr0  = thrs[0],  thr1  = thrs[1];
        float mem0 = 0.f, mem1 = 0.f;
        unsigned long long* zb = zbuf + (size_t)b * T_TOTAL * 8;

        for (int i = 0; i < SEQ_LEN; ++i) {
            if (tid < IN_DIM) xs[tid] = x[(i * BATCH + b) * IN_DIM + tid];
            __syncthreads();

            float cur0 = 0.f;
            #pragma unroll 8
            for (int k = 0; k < IN_DIM; ++k)
                cur0 = __fmaf_rn(xs[k], W0T[k * HIDDEN + tid], cur0);

            for (int s = 0; s < SPIKE_STEPS; ++s) {
                const int t = i * SPIKE_STEPS + s;

                // layer 0 LIF
                bool reset0 = (mem0 - thr0) > 0.f;
                mem0 = reset0 ? 0.f : __fadd_rn(__fmul_rn(beta0, mem0), cur0);
                bool z0 = (mem0 - thr0) > 0.f;

                unsigned long long balf = __ballot(z0);
                unsigned long long balc = __ballot(z0 && (tid >= REG_J));
                if (lane == 0) { zmf[wid] = balf; zmc[wid] = balc; }
                __syncthreads();

                // uniform mask words for the register tier (j < REG_J: words 0..2)
                unsigned mw0, mw1, mw2, mw3, mw4, mw5;
                {
                    unsigned long long w0 = zmf[0], w1 = zmf[1], w2 = zmf[2];
                    mw0 = __builtin_amdgcn_readfirstlane((unsigned)w0);
                    mw1 = __builtin_amdgcn_readfirstlane((unsigned)(w0 >> 32));
                    mw2 = __builtin_amdgcn_readfirstlane((unsigned)w1);
                    mw3 = __builtin_amdgcn_readfirstlane((unsigned)(w1 >> 32));
                    mw4 = __builtin_amdgcn_readfirstlane((unsigned)w2);
                    mw5 = __builtin_amdgcn_readfirstlane((unsigned)(w2 >> 32));
                }

                // compact ascending active list for j >= REG_J
                int nact;
                {
                    int pre = 0, total = 0;
                    #pragma unroll
                    for (int q = 0; q < 8; ++q) {
                        int p = __popcll(zmc[q]);
                        total += p;
                        if (q < wid) pre += p;
                    }
                    int rank = pre + __popcll(zmc[wid] & ((1ull << lane) - 1ull));
                    if (z0 && (tid >= REG_J)) act[rank] = tid;
                    nact = total;
                }
                __syncthreads();

                // ---- tier 1: register-resident rows (in ascending j order) ----
                float cur1 = 0.f;
                #pragma unroll
                for (int j = 0; j < 32; ++j)  if (mw0 & (1u << j)) cur1 = __fadd_rn(cur1, wr[j]);
                #pragma unroll
                for (int j = 0; j < 32; ++j)  if (mw1 & (1u << j)) cur1 = __fadd_rn(cur1, wr[32 + j]);
                #pragma unroll
                for (int j = 0; j < 32; ++j)  if (mw2 & (1u << j)) cur1 = __fadd_rn(cur1, wr[64 + j]);
                #pragma unroll
                for (int j = 0; j < 32; ++j)  if (mw3 & (1u << j)) cur1 = __fadd_rn(cur1, wr[96 + j]);
                #pragma unroll
                for (int j = 0; j < 32; ++j)  if (mw4 & (1u << j)) cur1 = __fadd_rn(cur1, wr[128 + j]);
                #pragma unroll
                for (int j = 0; j < 32; ++j)  if (mw5 & (1u << j)) cur1 = __fadd_rn(cur1, wr[160 + j]);

                // ---- tier 2: L2 rows j >= REG_J via active list ----
                {
                    int n = 0;
                    for (; n + 7 < nact; n += 8) {
                        float a0 = Wmat[act[n    ] * HIDDEN + tid];
                        float a1 = Wmat[act[n + 1] * HIDDEN + tid];
                        float a2 = Wmat[act[n + 2] * HIDDEN + tid];
                        float a3 = Wmat[act[n + 3] * HIDDEN + tid];
                        float a4 = Wmat[act[n + 4] * HIDDEN + tid];
                        float a5 = Wmat[act[n + 5] * HIDDEN + tid];
                        float a6 = Wmat[act[n + 6] * HIDDEN + tid];
                        float a7 = Wmat[act[n + 7] * HIDDEN + tid];
                        cur1 = __fadd_rn(cur1, a0);
                        cur1 = __fadd_rn(cur1, a1);
                        cur1 = __fadd_rn(cur1, a2);
                        cur1 = __fadd_rn(cur1, a3);
                        cur1 = __fadd_rn(cur1, a4);
                        cur1 = __fadd_rn(cur1, a5);
                        cur1 = __fadd_rn(cur1, a6);
                        cur1 = __fadd_rn(cur1, a7);
                    }
                    for (; n < nact; ++n)
                        cur1 = __fadd_rn(cur1, Wmat[act[n] * HIDDEN + tid]);
                }

                // layer 1 LIF
                bool reset1 = (mem1 - thr1) > 0.f;
                mem1 = reset1 ? 0.f : __fadd_rn(__fmul_rn(beta1, mem1), cur1);
                bool z1 = (mem1 - thr1) > 0.f;

                unsigned long long bal1 = __ballot(z1);
                if (lane == 0)
                    __hip_atomic_store(&zb[(size_t)t * 8 + wid], bal1,
                                       __ATOMIC_RELAXED, __HIP_MEMORY_SCOPE_AGENT);
                __syncthreads();   // vmcnt(0) drain before barrier => masks visible
                if (tid == 0)
                    __hip_atomic_store(&ctr[b], t + 1,
                                       __ATOMIC_RELAXED, __HIP_MEMORY_SCOPE_AGENT);
            }
        }
    } else {
        // ---------------- consumer: layer2 + output ----------------
        const float beta2 = betas[2];
        const float thr2  = thrs[2];
        const float wo0 = Wout[tid];
        const float wo1 = Wout[HIDDEN + tid];
        float mem2 = 0.f, mo0 = 0.f, mo1 = 0.f;
        const unsigned long long* zb = zbuf + (size_t)b * T_TOTAL * 8;

        for (int i = 0; i < SEQ_LEN; ++i) {
            float so0 = 0.f, so1 = 0.f;

            for (int s = 0; s < SPIKE_STEPS; ++s) {
                const int t = i * SPIKE_STEPS + s;

                if (tid == 0) {
                    while (__hip_atomic_load(&ctr[b], __ATOMIC_RELAXED,
                                             __HIP_MEMORY_SCOPE_AGENT) < t + 1)
                        __builtin_amdgcn_s_sleep(1);
                }
                __syncthreads();

                if (tid < 8)
                    zmf[tid] = __hip_atomic_load(&zb[(size_t)t * 8 + tid],
                                                 __ATOMIC_RELAXED, __HIP_MEMORY_SCOPE_AGENT);
                __syncthreads();

                bool z1 = (zmf[wid] >> lane) & 1ull;
                unsigned long long balc = __ballot(z1 && (tid >= REG_J));
                if (lane == 0) zmc[wid] = balc;
                __syncthreads();

                unsigned mw0, mw1, mw2, mw3, mw4, mw5;
                {
                    unsigned long long w0 = zmf[0], w1 = zmf[1], w2 = zmf[2];
                    mw0 = __builtin_amdgcn_readfirstlane((unsigned)w0);
                    mw1 = __builtin_amdgcn_readfirstlane((unsigned)(w0 >> 32));
                    mw2 = __builtin_amdgcn_readfirstlane((unsigned)w1);
                    mw3 = __builtin_amdgcn_readfirstlane((unsigned)(w1 >> 32));
                    mw4 = __builtin_amdgcn_readfirstlane((unsigned)w2);
                    mw5 = __builtin_amdgcn_readfirstlane((unsigned)(w2 >> 32));
                }

                int nact;
                {
                    int pre = 0, total = 0;
                    #pragma unroll
                    for (int q = 0; q < 8; ++q) {
                        int p = __popcll(zmc[q]);
                        total += p;
                        if (q < wid) pre += p;
                    }
                    int rank = pre + __popcll(zmc[wid] & ((1ull << lane) - 1ull));
                    if (z1 && (tid >= REG_J)) act[rank] = tid;
                    nact = total;
                }
                __syncthreads();

                // tier 1: register-resident rows
                float cur2 = 0.f;
                #pragma unroll
                for (int j = 0; j < 32; ++j)  if (mw0 & (1u << j)) cur2 = __fadd_rn(cur2, wr[j]);
                #pragma unroll
                for (int j = 0; j < 32; ++j)  if (mw1 & (1u << j)) cur2 = __fadd_rn(cur2, wr[32 + j]);
                #pragma unroll
                for (int j = 0; j < 32; ++j)  if (mw2 & (1u << j)) cur2 = __fadd_rn(cur2, wr[64 + j]);
                #pragma unroll
                for (int j = 0; j < 32; ++j)  if (mw3 & (1u << j)) cur2 = __fadd_rn(cur2, wr[96 + j]);
                #pragma unroll
                for (int j = 0; j < 32; ++j)  if (mw4 & (1u << j)) cur2 = __fadd_rn(cur2, wr[128 + j]);
                #pragma unroll
                for (int j = 0; j < 32; ++j)  if (mw5 & (1u << j)) cur2 = __fadd_rn(cur2, wr[160 + j]);

                // tier 2: L2 rows via active list
                {
                    int n = 0;
                    for (; n + 7 < nact; n += 8) {
                        float a0 = Wmat[act[n    ] * HIDDEN + tid];
                        float a1 = Wmat[act[n + 1] * HIDDEN + tid];
                        float a2 = Wmat[act[n + 2] * HIDDEN + tid];
                        float a3 = Wmat[act[n + 3] * HIDDEN + tid];
                        float a4 = Wmat[act[n + 4] * HIDDEN + tid];
                        float a5 = Wmat[act[n + 5] * HIDDEN + tid];
                        float a6 = Wmat[act[n + 6] * HIDDEN + tid];
                        float a7 = Wmat[act[n + 7] * HIDDEN + tid];
                        cur2 = __fadd_rn(cur2, a0);
                        cur2 = __fadd_rn(cur2, a1);
                        cur2 = __fadd_rn(cur2, a2);
                        cur2 = __fadd_rn(cur2, a3);
                        cur2 = __fadd_rn(cur2, a4);
                        cur2 = __fadd_rn(cur2, a5);
                        cur2 = __fadd_rn(cur2, a6);
                        cur2 = __fadd_rn(cur2, a7);
                    }
                    for (; n < nact; ++n)
                        cur2 = __fadd_rn(cur2, Wmat[act[n] * HIDDEN + tid]);
                }

                // layer 2 LIF
                bool reset2 = (mem2 - thr2) > 0.f;
                mem2 = reset2 ? 0.f : __fadd_rn(__fmul_rn(beta2, mem2), cur2);
                bool z2 = (mem2 - thr2) > 0.f;

                // output integrator
                float c0 = z2 ? wo0 : 0.f;
                float c1 = z2 ? wo1 : 0.f;
                #pragma unroll
                for (int off = 32; off > 0; off >>= 1) {
                    c0 += __shfl_down(c0, off);
                    c1 += __shfl_down(c1, off);
                }
                if (lane == 0) { red[wid * 2] = c0; red[wid * 2 + 1] = c1; }
                __syncthreads();
                if (tid == 0) {
                    float r0 = 0.f, r1 = 0.f;
                    #pragma unroll
                    for (int q = 0; q < 8; ++q) { r0 += red[q * 2]; r1 += red[q * 2 + 1]; }
                    mo0 += r0; mo1 += r1;
                    so0 += mo0; so1 += mo1;
                }
            }

            if (tid == 0) {
                out[(i * BATCH + b) * OUT_DIM + 0] = so0 / 7.0f;
                out[(i * BATCH + b) * OUT_DIM + 1] = so1 / 7.0f;
            }
        }
    }
}

extern "C" void kernel_launch(void* const* d_in, const int* in_sizes, int n_in,
                              void* d_out, int out_size, void* d_ws, size_t ws_size,
                              hipStream_t stream) {
    const float* x     = (const float*)d_in[0];
    const float* W0    = (const float*)d_in[1];
    const float* W1    = (const float*)d_in[2];
    const float* W2    = (const float*)d_in[3];
    const float* Wout  = (const float*)d_in[4];
    const float* betas = (const float*)d_in[5];
    const float* thrs  = (const float*)d_in[6];
    float* out = (float*)d_out;

    float* ws  = (float*)d_ws;
    float* W0T = ws + W0T_OFF;
    float* W1T = ws + W1T_OFF;
    float* W2T = ws + W2T_OFF;
    int* ctr = (int*)((char*)d_ws + CTR_BYTE_OFF);
    unsigned long long* zbuf = (unsigned long long*)((char*)d_ws + ZBUF_BYTE_OFF);

    {
        int n = HIDDEN * IN_DIM;
        transpose_kernel<<<(n + 255) / 256, 256, 0, stream>>>(W0, W0T, HIDDEN, IN_DIM);
    }
    {
        int n = HIDDEN * HIDDEN;
        transpose_kernel<<<(n + 255) / 256, 256, 0, stream>>>(W1, W1T, HIDDEN, HIDDEN);
        transpose_kernel<<<(n + 255) / 256, 256, 0, stream>>>(W2, W2T, HIDDEN, HIDDEN);
    }

    hipMemsetAsync((char*)d_ws + CTR_BYTE_OFF, 0, 1024, stream);

    snn_reg_kernel<<<2 * BATCH, HIDDEN, 0, stream>>>(
        x, Wout, betas, thrs, W0T, W1T, W2T, zbuf, ctr, out);
}

// Round 6
// 5173.610 us; speedup vs baseline: 1.4704x; 1.2149x over previous
//
#include <hip/hip_runtime.h>

#define SEQ_LEN 256
#define SPIKE_STEPS 7
#define T_TOTAL (SEQ_LEN * SPIKE_STEPS)
#define BATCH 128
#define IN_DIM 96
#define HIDDEN 512
#define OUT_DIM 2

#define H_LDS 64                         // columns served from LDS: h in [448,512) = wave 7
#define H_GLB (HIDDEN - H_LDS)           // 448
#define LDS_DYN_BYTES (HIDDEN * H_LDS * 4)   // 512*64*4 = 131072 B (check: +2560 static = 133.6 KB <= 160 KB)

// d_ws layout: W0T [96*512] | W1T [512*512] | W2T [512*512] | ctr[128] | zbuf[B][T][8] u64
#define W0T_OFF 0
#define W1T_OFF (IN_DIM * HIDDEN)
#define W2T_OFF (W1T_OFF + HIDDEN * HIDDEN)
#define CTR_BYTE_OFF ((size_t)(W2T_OFF + HIDDEN * HIDDEN) * sizeof(float))
#define ZBUF_BYTE_OFF (CTR_BYTE_OFF + 1024)

__global__ void transpose_kernel(const float* __restrict__ in, float* __restrict__ out,
                                 int rows, int cols) {
    int idx = blockIdx.x * blockDim.x + threadIdx.x;
    if (idx < rows * cols) {
        int r = idx / cols, c = idx - r * cols;
        out[c * rows + r] = in[idx];
    }
}

// Round-2 two-stage pipeline (even blocks: layer0+layer1; odd: layer2+output),
// per-step sync, PLUS a wave-aligned LDS weight slice: wave 7 (h>=448) reads
// its weight column from a 128 KB LDS-resident slice (filled once) instead of
// L2. Waves 0-6 are pure-L2, wave 7 pure-LDS -> no intra-wave divergence.
// Per-h add order identical to round 2 => bit-identical results.
__launch_bounds__(512, 1)
__global__ void snn_lds_kernel(const float* __restrict__ x,     // [256,128,96]
                               const float* __restrict__ Wout,  // [2,512]
                               const float* __restrict__ betas, // [3]
                               const float* __restrict__ thrs,  // [3]
                               const float* __restrict__ W0T,   // [96,512]
                               const float* __restrict__ W1T,   // [512,512]
                               const float* __restrict__ W2T,   // [512,512]
                               unsigned long long* __restrict__ zbuf,
                               int* __restrict__ ctr,
                               float* __restrict__ out)         // [256,128,2]
{
    const int b    = blockIdx.x >> 1;
    const int role = blockIdx.x & 1;
    const int tid  = threadIdx.x;
    const int lane = tid & 63;
    const int wid  = tid >> 6;

    __shared__ float xs[IN_DIM];
    __shared__ unsigned long long zm[8];
    __shared__ int act[HIDDEN];
    __shared__ float red[16];
    extern __shared__ float Wlds[];   // [512][H_LDS]: columns 448..511 of role's matrix

    // ---- one-time fill of the LDS weight slice (role-dependent matrix) ----
    {
        const float* Wsrc = (role == 0) ? W1T : W2T;
        const float4* src4 = (const float4*)Wsrc;
        float4* dst4 = (float4*)Wlds;
        // row j, cols [448,512): global float4 idx j*128 + 112 + c4, c4 in [0,16)
        // LDS float4 idx j*16 + c4.  Total 512*16 = 8192 float4s.
        for (int idx = tid; idx < HIDDEN * (H_LDS / 4); idx += 512) {
            int j  = idx >> 4;
            int c4 = idx & 15;
            dst4[idx] = src4[j * (HIDDEN / 4) + (H_GLB / 4) + c4];
        }
    }
    __syncthreads();

    if (role == 0) {
        // ---------------- producer: layer0 + layer1 ----------------
        const float beta0 = betas[0], beta1 = betas[1];
        const float thr0  = thrs[0],  thr1  = thrs[1];
        float mem0 = 0.f, mem1 = 0.f;
        unsigned long long* zb = zbuf + (size_t)b * T_TOTAL * 8;

        for (int i = 0; i < SEQ_LEN; ++i) {
            if (tid < IN_DIM) xs[tid] = x[(i * BATCH + b) * IN_DIM + tid];
            __syncthreads();

            float cur0 = 0.f;
            #pragma unroll 8
            for (int k = 0; k < IN_DIM; ++k)
                cur0 = __fmaf_rn(xs[k], W0T[k * HIDDEN + tid], cur0);

            for (int s = 0; s < SPIKE_STEPS; ++s) {
                const int t = i * SPIKE_STEPS + s;

                // layer 0 LIF
                bool reset0 = (mem0 - thr0) > 0.f;
                mem0 = reset0 ? 0.f : __fadd_rn(__fmul_rn(beta0, mem0), cur0);
                bool z0 = (mem0 - thr0) > 0.f;
                unsigned long long bal = __ballot(z0);
                if (lane == 0) zm[wid] = bal;
                __syncthreads();

                int nact;
                {
                    int pre = 0, total = 0;
                    #pragma unroll
                    for (int q = 0; q < 8; ++q) {
                        int p = __popcll(zm[q]);
                        total += p;
                        if (q < wid) pre += p;
                    }
                    int rank = pre + __popcll(zm[wid] & ((1ull << lane) - 1ull));
                    if (z0) act[rank] = tid;
                    nact = total;
                }
                __syncthreads();

                // layer1 current: in-order sum of active W1 rows (port per wave)
                float cur1 = 0.f;
                if (tid < H_GLB) {
                    int n = 0;
                    for (; n + 7 < nact; n += 8) {
                        float a0 = W1T[act[n    ] * HIDDEN + tid];
                        float a1 = W1T[act[n + 1] * HIDDEN + tid];
                        float a2 = W1T[act[n + 2] * HIDDEN + tid];
                        float a3 = W1T[act[n + 3] * HIDDEN + tid];
                        float a4 = W1T[act[n + 4] * HIDDEN + tid];
                        float a5 = W1T[act[n + 5] * HIDDEN + tid];
                        float a6 = W1T[act[n + 6] * HIDDEN + tid];
                        float a7 = W1T[act[n + 7] * HIDDEN + tid];
                        cur1 = __fadd_rn(cur1, a0);
                        cur1 = __fadd_rn(cur1, a1);
                        cur1 = __fadd_rn(cur1, a2);
                        cur1 = __fadd_rn(cur1, a3);
                        cur1 = __fadd_rn(cur1, a4);
                        cur1 = __fadd_rn(cur1, a5);
                        cur1 = __fadd_rn(cur1, a6);
                        cur1 = __fadd_rn(cur1, a7);
                    }
                    for (; n < nact; ++n)
                        cur1 = __fadd_rn(cur1, W1T[act[n] * HIDDEN + tid]);
                } else {
                    const int cl = tid - H_GLB;
                    int n = 0;
                    for (; n + 7 < nact; n += 8) {
                        float a0 = Wlds[act[n    ] * H_LDS + cl];
                        float a1 = Wlds[act[n + 1] * H_LDS + cl];
                        float a2 = Wlds[act[n + 2] * H_LDS + cl];
                        float a3 = Wlds[act[n + 3] * H_LDS + cl];
                        float a4 = Wlds[act[n + 4] * H_LDS + cl];
                        float a5 = Wlds[act[n + 5] * H_LDS + cl];
                        float a6 = Wlds[act[n + 6] * H_LDS + cl];
                        float a7 = Wlds[act[n + 7] * H_LDS + cl];
                        cur1 = __fadd_rn(cur1, a0);
                        cur1 = __fadd_rn(cur1, a1);
                        cur1 = __fadd_rn(cur1, a2);
                        cur1 = __fadd_rn(cur1, a3);
                        cur1 = __fadd_rn(cur1, a4);
                        cur1 = __fadd_rn(cur1, a5);
                        cur1 = __fadd_rn(cur1, a6);
                        cur1 = __fadd_rn(cur1, a7);
                    }
                    for (; n < nact; ++n)
                        cur1 = __fadd_rn(cur1, Wlds[act[n] * H_LDS + cl]);
                }

                // layer 1 LIF
                bool reset1 = (mem1 - thr1) > 0.f;
                mem1 = reset1 ? 0.f : __fadd_rn(__fmul_rn(beta1, mem1), cur1);
                bool z1 = (mem1 - thr1) > 0.f;

                unsigned long long bal1 = __ballot(z1);
                if (lane == 0)
                    __hip_atomic_store(&zb[(size_t)t * 8 + wid], bal1,
                                       __ATOMIC_RELAXED, __HIP_MEMORY_SCOPE_AGENT);
                __syncthreads();   // vmcnt(0) drain before barrier => masks visible
                if (tid == 0)
                    __hip_atomic_store(&ctr[b], t + 1,
                                       __ATOMIC_RELAXED, __HIP_MEMORY_SCOPE_AGENT);
            }
        }
    } else {
        // ---------------- consumer: layer2 + output ----------------
        const float beta2 = betas[2];
        const float thr2  = thrs[2];
        const float wo0 = Wout[tid];
        const float wo1 = Wout[HIDDEN + tid];
        float mem2 = 0.f, mo0 = 0.f, mo1 = 0.f;
        const unsigned long long* zb = zbuf + (size_t)b * T_TOTAL * 8;

        for (int i = 0; i < SEQ_LEN; ++i) {
            float so0 = 0.f, so1 = 0.f;

            for (int s = 0; s < SPIKE_STEPS; ++s) {
                const int t = i * SPIKE_STEPS + s;

                if (tid == 0) {
                    while (__hip_atomic_load(&ctr[b], __ATOMIC_RELAXED,
                                             __HIP_MEMORY_SCOPE_AGENT) < t + 1)
                        __builtin_amdgcn_s_sleep(1);
                }
                __syncthreads();

                if (tid < 8)
                    zm[tid] = __hip_atomic_load(&zb[(size_t)t * 8 + tid],
                                                __ATOMIC_RELAXED, __HIP_MEMORY_SCOPE_AGENT);
                __syncthreads();

                bool z1 = (zm[wid] >> lane) & 1ull;
                int nact;
                {
                    int pre = 0, total = 0;
                    #pragma unroll
                    for (int q = 0; q < 8; ++q) {
                        int p = __popcll(zm[q]);
                        total += p;
                        if (q < wid) pre += p;
                    }
                    int rank = pre + __popcll(zm[wid] & ((1ull << lane) - 1ull));
                    if (z1) act[rank] = tid;
                    nact = total;
                }
                __syncthreads();

                // layer2 current (port per wave)
                float cur2 = 0.f;
                if (tid < H_GLB) {
                    int n = 0;
                    for (; n + 7 < nact; n += 8) {
                        float a0 = W2T[act[n    ] * HIDDEN + tid];
                        float a1 = W2T[act[n + 1] * HIDDEN + tid];
                        float a2 = W2T[act[n + 2] * HIDDEN + tid];
                        float a3 = W2T[act[n + 3] * HIDDEN + tid];
                        float a4 = W2T[act[n + 4] * HIDDEN + tid];
                        float a5 = W2T[act[n + 5] * HIDDEN + tid];
                        float a6 = W2T[act[n + 6] * HIDDEN + tid];
                        float a7 = W2T[act[n + 7] * HIDDEN + tid];
                        cur2 = __fadd_rn(cur2, a0);
                        cur2 = __fadd_rn(cur2, a1);
                        cur2 = __fadd_rn(cur2, a2);
                        cur2 = __fadd_rn(cur2, a3);
                        cur2 = __fadd_rn(cur2, a4);
                        cur2 = __fadd_rn(cur2, a5);
                        cur2 = __fadd_rn(cur2, a6);
                        cur2 = __fadd_rn(cur2, a7);
                    }
                    for (; n < nact; ++n)
                        cur2 = __fadd_rn(cur2, W2T[act[n] * HIDDEN + tid]);
                } else {
                    const int cl = tid - H_GLB;
                    int n = 0;
                    for (; n + 7 < nact; n += 8) {
                        float a0 = Wlds[act[n    ] * H_LDS + cl];
                        float a1 = Wlds[act[n + 1] * H_LDS + cl];
                        float a2 = Wlds[act[n + 2] * H_LDS + cl];
                        float a3 = Wlds[act[n + 3] * H_LDS + cl];
                        float a4 = Wlds[act[n + 4] * H_LDS + cl];
                        float a5 = Wlds[act[n + 5] * H_LDS + cl];
                        float a6 = Wlds[act[n + 6] * H_LDS + cl];
                        float a7 = Wlds[act[n + 7] * H_LDS + cl];
                        cur2 = __fadd_rn(cur2, a0);
                        cur2 = __fadd_rn(cur2, a1);
                        cur2 = __fadd_rn(cur2, a2);
                        cur2 = __fadd_rn(cur2, a3);
                        cur2 = __fadd_rn(cur2, a4);
                        cur2 = __fadd_rn(cur2, a5);
                        cur2 = __fadd_rn(cur2, a6);
                        cur2 = __fadd_rn(cur2, a7);
                    }
                    for (; n < nact; ++n)
                        cur2 = __fadd_rn(cur2, Wlds[act[n] * H_LDS + cl]);
                }

                // layer 2 LIF
                bool reset2 = (mem2 - thr2) > 0.f;
                mem2 = reset2 ? 0.f : __fadd_rn(__fmul_rn(beta2, mem2), cur2);
                bool z2 = (mem2 - thr2) > 0.f;

                // output integrator
                float c0 = z2 ? wo0 : 0.f;
                float c1 = z2 ? wo1 : 0.f;
                #pragma unroll
                for (int off = 32; off > 0; off >>= 1) {
                    c0 += __shfl_down(c0, off);
                    c1 += __shfl_down(c1, off);
                }
                if (lane == 0) { red[wid * 2] = c0; red[wid * 2 + 1] = c1; }
                __syncthreads();
                if (tid == 0) {
                    float r0 = 0.f, r1 = 0.f;
                    #pragma unroll
                    for (int q = 0; q < 8; ++q) { r0 += red[q * 2]; r1 += red[q * 2 + 1]; }
                    mo0 += r0; mo1 += r1;
                    so0 += mo0; so1 += mo1;
                }
            }

            if (tid == 0) {
                out[(i * BATCH + b) * OUT_DIM + 0] = so0 / 7.0f;
                out[(i * BATCH + b) * OUT_DIM + 1] = so1 / 7.0f;
            }
        }
    }
}

extern "C" void kernel_launch(void* const* d_in, const int* in_sizes, int n_in,
                              void* d_out, int out_size, void* d_ws, size_t ws_size,
                              hipStream_t stream) {
    const float* x     = (const float*)d_in[0];
    const float* W0    = (const float*)d_in[1];
    const float* W1    = (const float*)d_in[2];
    const float* W2    = (const float*)d_in[3];
    const float* Wout  = (const float*)d_in[4];
    const float* betas = (const float*)d_in[5];
    const float* thrs  = (const float*)d_in[6];
    float* out = (float*)d_out;

    float* ws  = (float*)d_ws;
    float* W0T = ws + W0T_OFF;
    float* W1T = ws + W1T_OFF;
    float* W2T = ws + W2T_OFF;
    int* ctr = (int*)((char*)d_ws + CTR_BYTE_OFF);
    unsigned long long* zbuf = (unsigned long long*)((char*)d_ws + ZBUF_BYTE_OFF);

    // opt-in for >64 KB dynamic LDS (host-side attribute, not a stream op;
    // idempotent, safe under graph capture)
    static bool attr_set = false;
    (void)hipFuncSetAttribute((const void*)snn_lds_kernel,
                              hipFuncAttributeMaxDynamicSharedMemorySize,
                              LDS_DYN_BYTES);

    {
        int n = HIDDEN * IN_DIM;
        transpose_kernel<<<(n + 255) / 256, 256, 0, stream>>>(W0, W0T, HIDDEN, IN_DIM);
    }
    {
        int n = HIDDEN * HIDDEN;
        transpose_kernel<<<(n + 255) / 256, 256, 0, stream>>>(W1, W1T, HIDDEN, HIDDEN);
        transpose_kernel<<<(n + 255) / 256, 256, 0, stream>>>(W2, W2T, HIDDEN, HIDDEN);
    }

    hipMemsetAsync((char*)d_ws + CTR_BYTE_OFF, 0, 1024, stream);

    snn_lds_kernel<<<2 * BATCH, HIDDEN, LDS_DYN_BYTES, stream>>>(
        x, Wout, betas, thrs, W0T, W1T, W2T, zbuf, ctr, out);
}

// Round 7
// 4293.365 us; speedup vs baseline: 1.7719x; 1.2050x over previous
//
#include <hip/hip_runtime.h>

#define SEQ_LEN 256
#define SPIKE_STEPS 7
#define T_TOTAL (SEQ_LEN * SPIKE_STEPS)
#define BATCH 128
#define IN_DIM 96
#define HIDDEN 512
#define OUT_DIM 2

// Weight buffers carry an extra all-zero row (index 512) used to pad the
// active list to a multiple of 16 — enables a fixed-trip-count, software-
// pipelined inner loop with two 16-load groups in flight.
#define WROWS (HIDDEN + 1)

// d_ws layout: W0T [96*512] | W1T [513*512] | W2T [513*512] | ctr[128] | zbuf[B][T][8] u64
#define W0T_OFF 0
#define W1T_OFF (IN_DIM * HIDDEN)
#define W2T_OFF (W1T_OFF + WROWS * HIDDEN)
#define CTR_BYTE_OFF ((size_t)(W2T_OFF + WROWS * HIDDEN) * sizeof(float))   // 2,297,856 (1KB-aligned)
#define ZBUF_BYTE_OFF (CTR_BYTE_OFF + 1024)

__global__ void transpose_kernel(const float* __restrict__ in, float* __restrict__ out,
                                 int rows, int cols) {
    int idx = blockIdx.x * blockDim.x + threadIdx.x;
    if (idx < rows * cols) {
        int r = idx / cols, c = idx - r * cols;
        out[c * rows + r] = in[idx];
    }
}

// Sum of active weight rows, software-pipelined: 16-row groups, next group's
// loads issued before current group's adds => compiler emits vmcnt(16) not
// vmcnt(0); ~32 outstanding loads per thread. npad multiple of 16 via zero-row
// padding => no remainder loop. Add order = ascending act + trailing zeros =>
// bit-identical to the simple in-order sum.
__device__ __forceinline__ float row_sum_pipelined(const float* __restrict__ W,
                                                   const int* __restrict__ act,
                                                   int npad, int tid) {
    float cur = 0.f;
    if (npad > 0) {
        float buf[16];
        #pragma unroll
        for (int k = 0; k < 16; ++k) buf[k] = W[act[k] * HIDDEN + tid];
        for (int n = 16; n < npad; n += 16) {
            float nxt[16];
            #pragma unroll
            for (int k = 0; k < 16; ++k) nxt[k] = W[act[n + k] * HIDDEN + tid];
            #pragma unroll
            for (int k = 0; k < 16; ++k) cur = __fadd_rn(cur, buf[k]);
            #pragma unroll
            for (int k = 0; k < 16; ++k) buf[k] = nxt[k];
        }
        #pragma unroll
        for (int k = 0; k < 16; ++k) cur = __fadd_rn(cur, buf[k]);
    }
    return cur;
}

// Round-2 two-stage pipeline: even blocks = producer (layer0+layer1),
// odd = consumer (layer2+output); per-step mask handoff through L2 with
// relaxed agent-scope atomics.
__launch_bounds__(512, 1)
__global__ void snn_pipe_kernel(const float* __restrict__ x,     // [256,128,96]
                                const float* __restrict__ Wout,  // [2,512]
                                const float* __restrict__ betas, // [3]
                                const float* __restrict__ thrs,  // [3]
                                const float* __restrict__ W0T,   // [96,512]
                                const float* __restrict__ W1T,   // [513,512]
                                const float* __restrict__ W2T,   // [513,512]
                                unsigned long long* __restrict__ zbuf,
                                int* __restrict__ ctr,
                                float* __restrict__ out)         // [256,128,2]
{
    const int b    = blockIdx.x >> 1;
    const int role = blockIdx.x & 1;
    const int tid  = threadIdx.x;
    const int lane = tid & 63;
    const int wid  = tid >> 6;

    __shared__ float xs[IN_DIM];
    __shared__ unsigned long long zm[8];
    __shared__ int act[HIDDEN];
    __shared__ float red[16];

    if (role == 0) {
        // ---------------- producer: layer0 + layer1 ----------------
        const float beta0 = betas[0], beta1 = betas[1];
        const float thr0  = thrs[0],  thr1  = thrs[1];
        float mem0 = 0.f, mem1 = 0.f;
        unsigned long long* zb = zbuf + (size_t)b * T_TOTAL * 8;

        for (int i = 0; i < SEQ_LEN; ++i) {
            if (tid < IN_DIM) xs[tid] = x[(i * BATCH + b) * IN_DIM + tid];
            __syncthreads();

            float cur0 = 0.f;
            #pragma unroll 8
            for (int k = 0; k < IN_DIM; ++k)
                cur0 = __fmaf_rn(xs[k], W0T[k * HIDDEN + tid], cur0);

            for (int s = 0; s < SPIKE_STEPS; ++s) {
                const int t = i * SPIKE_STEPS + s;

                // layer 0 LIF
                bool reset0 = (mem0 - thr0) > 0.f;
                mem0 = reset0 ? 0.f : __fadd_rn(__fmul_rn(beta0, mem0), cur0);
                bool z0 = (mem0 - thr0) > 0.f;
                unsigned long long bal = __ballot(z0);
                if (lane == 0) zm[wid] = bal;
                __syncthreads();

                int nact, npad;
                {
                    int pre = 0, total = 0;
                    #pragma unroll
                    for (int q = 0; q < 8; ++q) {
                        int p = __popcll(zm[q]);
                        total += p;
                        if (q < wid) pre += p;
                    }
                    int rank = pre + __popcll(zm[wid] & ((1ull << lane) - 1ull));
                    if (z0) act[rank] = tid;
                    nact = total;
                    npad = (nact + 15) & ~15;
                    if (tid < npad - nact) act[nact + tid] = HIDDEN;  // zero-row pads
                }
                __syncthreads();

                float cur1 = row_sum_pipelined(W1T, act, npad, tid);

                // layer 1 LIF
                bool reset1 = (mem1 - thr1) > 0.f;
                mem1 = reset1 ? 0.f : __fadd_rn(__fmul_rn(beta1, mem1), cur1);
                bool z1 = (mem1 - thr1) > 0.f;

                unsigned long long bal1 = __ballot(z1);
                if (lane == 0)
                    __hip_atomic_store(&zb[(size_t)t * 8 + wid], bal1,
                                       __ATOMIC_RELAXED, __HIP_MEMORY_SCOPE_AGENT);
                __syncthreads();   // vmcnt(0) drain before barrier => masks visible
                if (tid == 0)
                    __hip_atomic_store(&ctr[b], t + 1,
                                       __ATOMIC_RELAXED, __HIP_MEMORY_SCOPE_AGENT);
            }
        }
    } else {
        // ---------------- consumer: layer2 + output ----------------
        const float beta2 = betas[2];
        const float thr2  = thrs[2];
        const float wo0 = Wout[tid];
        const float wo1 = Wout[HIDDEN + tid];
        float mem2 = 0.f, mo0 = 0.f, mo1 = 0.f;
        const unsigned long long* zb = zbuf + (size_t)b * T_TOTAL * 8;

        for (int i = 0; i < SEQ_LEN; ++i) {
            float so0 = 0.f, so1 = 0.f;

            for (int s = 0; s < SPIKE_STEPS; ++s) {
                const int t = i * SPIKE_STEPS + s;

                if (tid == 0) {
                    while (__hip_atomic_load(&ctr[b], __ATOMIC_RELAXED,
                                             __HIP_MEMORY_SCOPE_AGENT) < t + 1)
                        __builtin_amdgcn_s_sleep(1);
                }
                __syncthreads();

                if (tid < 8)
                    zm[tid] = __hip_atomic_load(&zb[(size_t)t * 8 + tid],
                                                __ATOMIC_RELAXED, __HIP_MEMORY_SCOPE_AGENT);
                __syncthreads();

                bool z1 = (zm[wid] >> lane) & 1ull;
                int nact, npad;
                {
                    int pre = 0, total = 0;
                    #pragma unroll
                    for (int q = 0; q < 8; ++q) {
                        int p = __popcll(zm[q]);
                        total += p;
                        if (q < wid) pre += p;
                    }
                    int rank = pre + __popcll(zm[wid] & ((1ull << lane) - 1ull));
                    if (z1) act[rank] = tid;
                    nact = total;
                    npad = (nact + 15) & ~15;
                    if (tid < npad - nact) act[nact + tid] = HIDDEN;  // zero-row pads
                }
                __syncthreads();

                float cur2 = row_sum_pipelined(W2T, act, npad, tid);

                // layer 2 LIF
                bool reset2 = (mem2 - thr2) > 0.f;
                mem2 = reset2 ? 0.f : __fadd_rn(__fmul_rn(beta2, mem2), cur2);
                bool z2 = (mem2 - thr2) > 0.f;

                // output integrator
                float c0 = z2 ? wo0 : 0.f;
                float c1 = z2 ? wo1 : 0.f;
                #pragma unroll
                for (int off = 32; off > 0; off >>= 1) {
                    c0 += __shfl_down(c0, off);
                    c1 += __shfl_down(c1, off);
                }
                if (lane == 0) { red[wid * 2] = c0; red[wid * 2 + 1] = c1; }
                __syncthreads();
                if (tid == 0) {
                    float r0 = 0.f, r1 = 0.f;
                    #pragma unroll
                    for (int q = 0; q < 8; ++q) { r0 += red[q * 2]; r1 += red[q * 2 + 1]; }
                    mo0 += r0; mo1 += r1;
                    so0 += mo0; so1 += mo1;
                }
            }

            if (tid == 0) {
                out[(i * BATCH + b) * OUT_DIM + 0] = so0 / 7.0f;
                out[(i * BATCH + b) * OUT_DIM + 1] = so1 / 7.0f;
            }
        }
    }
}

extern "C" void kernel_launch(void* const* d_in, const int* in_sizes, int n_in,
                              void* d_out, int out_size, void* d_ws, size_t ws_size,
                              hipStream_t stream) {
    const float* x     = (const float*)d_in[0];
    const float* W0    = (const float*)d_in[1];
    const float* W1    = (const float*)d_in[2];
    const float* W2    = (const float*)d_in[3];
    const float* Wout  = (const float*)d_in[4];
    const float* betas = (const float*)d_in[5];
    const float* thrs  = (const float*)d_in[6];
    float* out = (float*)d_out;

    float* ws  = (float*)d_ws;
    float* W0T = ws + W0T_OFF;
    float* W1T = ws + W1T_OFF;
    float* W2T = ws + W2T_OFF;
    int* ctr = (int*)((char*)d_ws + CTR_BYTE_OFF);
    unsigned long long* zbuf = (unsigned long long*)((char*)d_ws + ZBUF_BYTE_OFF);

    {
        int n = HIDDEN * IN_DIM;
        transpose_kernel<<<(n + 255) / 256, 256, 0, stream>>>(W0, W0T, HIDDEN, IN_DIM);
    }
    {
        int n = HIDDEN * HIDDEN;
        transpose_kernel<<<(n + 255) / 256, 256, 0, stream>>>(W1, W1T, HIDDEN, HIDDEN);
        transpose_kernel<<<(n + 255) / 256, 256, 0, stream>>>(W2, W2T, HIDDEN, HIDDEN);
    }

    // zero the pad row (index 512) of W1T/W2T, and the progress counters
    hipMemsetAsync(W1T + (size_t)HIDDEN * HIDDEN, 0, HIDDEN * sizeof(float), stream);
    hipMemsetAsync(W2T + (size_t)HIDDEN * HIDDEN, 0, HIDDEN * sizeof(float), stream);
    hipMemsetAsync((char*)d_ws + CTR_BYTE_OFF, 0, 1024, stream);

    snn_pipe_kernel<<<2 * BATCH, HIDDEN, 0, stream>>>(
        x, Wout, betas, thrs, W0T, W1T, W2T, zbuf, ctr, out);
}